// Round 2
// baseline (478.614 us; speedup 1.0000x reference)
//
#include <hip/hip_runtime.h>
#include <stdint.h>

typedef __attribute__((ext_vector_type(4))) int i32x4;

#define QLIM 127.0f
#define BM 128
#define BN 128
#define BKB 128   // staged K-bytes per tile (i8 elements); 2 MFMA K-substeps of 64

__device__ __forceinline__ int quant_pack4(float4 v, float s) {
    float a0 = rintf(fminf(fmaxf(v.x * s, -QLIM), QLIM));
    float a1 = rintf(fminf(fmaxf(v.y * s, -QLIM), QLIM));
    float a2 = rintf(fminf(fmaxf(v.z * s, -QLIM), QLIM));
    float a3 = rintf(fminf(fmaxf(v.w * s, -QLIM), QLIM));
    return ((int)a0 & 255) | (((int)a1 & 255) << 8) |
           (((int)a2 & 255) << 16) | (((int)a3 & 255) << 24);
}

// fp32 -> int8 quantization. One float4 (16B) load + one int (4B) store per
// thread-iter: lane-contiguous, fully coalesced (R1 version strode 64B/lane).
__global__ void quantize_kernel(const float4* __restrict__ in, int* __restrict__ q,
                                const float* __restrict__ amax, long n4) {
    const float s = QLIM / amax[0];
    const long stride = (long)gridDim.x * blockDim.x;
    for (long i = (long)blockIdx.x * blockDim.x + threadIdx.x; i < n4; i += stride)
        q[i] = quant_pack4(in[i], s);
}

// int8 GEMM: C[M][N] = A[M][K]*B[N][K]^T, fp32 epilogue (rescale + bias).
// m97 byte-geometry: 128x128 tile, LDS rows of 128B, 4 waves (2x2) each owning
// a 64x64 output sub-tile; mfma_i32_16x16x64_i8, 2 K-substeps per staged tile.
__global__ __launch_bounds__(256) void gemm_i8_kernel(
    const signed char* __restrict__ A,   // qx [M][K]
    const signed char* __restrict__ B,   // qw [N][K]
    const float* __restrict__ bias,      // [N]
    const float* __restrict__ amax,
    const float* __restrict__ amax_w,
    float* __restrict__ C,               // [M][N]
    int M, int N, int K)
{
    __shared__ signed char As[BM * BKB];  // 16 KB, row-major [128][128]
    __shared__ signed char Bs[BN * BKB];  // 16 KB

    const int tid  = threadIdx.x;
    const int wid  = tid >> 6;
    const int lane = tid & 63;
    const int wm   = wid >> 1;
    const int wn   = wid & 1;

    // T1: XCD-aware bijective swizzle (nwg % 8 == 0 guaranteed by launch)
    const int nwg = gridDim.x;
    const int cpx = nwg >> 3;
    const int bid = (int)blockIdx.x;
    const int swz = (bid & 7) * cpx + (bid >> 3);
    const int ntn = N / BN;
    const int bm  = swz / ntn;
    const int bn  = swz % ntn;

    // staging: round j covers rows [j*32, j*32+32); thread t -> row j*32 + t/8,
    // byte col (t%8)*16. Linear LDS == row-major [128][128B].
    const int srow = tid >> 3;            // 0..31
    const int scol = (tid & 7) << 4;      // 0..112

    const signed char* a_base = A + (size_t)(bm * BM) * K;
    const signed char* b_base = B + (size_t)(bn * BN) * K;

    // fragment: lane l -> row (l&15), 16 contiguous K-bytes at (l>>4)*16
    const int fr = lane & 15;
    const int fk = (lane >> 4) << 4;

    i32x4 acc[4][4] = {};

    for (int k0 = 0; k0 < K; k0 += BKB) {
#pragma unroll
        for (int j = 0; j < 4; ++j) {
            const signed char* ag = a_base + (size_t)(j * 32 + srow) * K + k0 + scol;
            const signed char* bg = b_base + (size_t)(j * 32 + srow) * K + k0 + scol;
            // dest = wave-uniform base; HW adds lane*16 (linear, matches row-major)
            __builtin_amdgcn_global_load_lds(
                (const __attribute__((address_space(1))) void*)ag,
                (__attribute__((address_space(3))) void*)(As + j * 4096 + wid * 1024),
                16, 0, 0);
            __builtin_amdgcn_global_load_lds(
                (const __attribute__((address_space(1))) void*)bg,
                (__attribute__((address_space(3))) void*)(Bs + j * 4096 + wid * 1024),
                16, 0, 0);
        }
        __syncthreads();

#pragma unroll
        for (int kk = 0; kk < 2; ++kk) {
            i32x4 a_frag[4], b_frag[4];
#pragma unroll
            for (int m = 0; m < 4; ++m)
                a_frag[m] = *(const i32x4*)(As + (wm * 64 + m * 16 + fr) * BKB + kk * 64 + fk);
#pragma unroll
            for (int n = 0; n < 4; ++n)
                b_frag[n] = *(const i32x4*)(Bs + (wn * 64 + n * 16 + fr) * BKB + kk * 64 + fk);

#pragma unroll
            for (int m = 0; m < 4; ++m)
#pragma unroll
                for (int n = 0; n < 4; ++n)
                    acc[m][n] = __builtin_amdgcn_mfma_i32_16x16x64_i8(
                        a_frag[m], b_frag[n], acc[m][n], 0, 0, 0);
        }
        __syncthreads();
    }

    // epilogue: out = acc * (amax*amax_w/127^2) + bias
    const float sa  = QLIM / amax[0];
    const float sw  = QLIM / amax_w[0];
    const float inv = 1.0f / (sa * sw);
    const int row0 = bm * BM + wm * 64;
    const int col0 = bn * BN + wn * 64;
#pragma unroll
    for (int m = 0; m < 4; ++m) {
#pragma unroll
        for (int n = 0; n < 4; ++n) {
            const int colc = col0 + n * 16 + fr;
            const float bv = bias[colc];
#pragma unroll
            for (int r = 0; r < 4; ++r) {
                const int rowc = row0 + m * 16 + ((lane >> 4) << 2) + r;
                C[(size_t)rowc * N + colc] = (float)acc[m][n][r] * inv + bv;
            }
        }
    }
}

extern "C" void kernel_launch(void* const* d_in, const int* in_sizes, int n_in,
                              void* d_out, int out_size, void* d_ws, size_t ws_size,
                              hipStream_t stream) {
    const float* x      = (const float*)d_in[0];
    const float* w      = (const float*)d_in[1];
    const float* bias   = (const float*)d_in[2];
    const float* amax   = (const float*)d_in[3];
    const float* amax_w = (const float*)d_in[4];
    float* out = (float*)d_out;

    const int N = in_sizes[2];                 // 4096
    const int K = in_sizes[1] / N;             // 4096
    const int M = in_sizes[0] / K;             // 8192

    signed char* qx = (signed char*)d_ws;           // M*K bytes (32 MB)
    signed char* qw = qx + (size_t)M * K;           // N*K bytes (16 MB)

    const long nx4 = (long)M * K / 4;
    const long nw4 = (long)N * K / 4;
    quantize_kernel<<<2048, 256, 0, stream>>>((const float4*)x, (int*)qx, amax, nx4);
    quantize_kernel<<<1024, 256, 0, stream>>>((const float4*)w, (int*)qw, amax_w, nw4);

    const int nblocks = (M / BM) * (N / BN);   // 64*32 = 2048, %8 == 0
    gemm_i8_kernel<<<nblocks, 256, 0, stream>>>(qx, qw, bias, amax, amax_w, out, M, N, K);
}

// Round 3
// 405.866 us; speedup vs baseline: 1.1792x; 1.1792x over previous
//
#include <hip/hip_runtime.h>
#include <stdint.h>

typedef __attribute__((ext_vector_type(4))) int i32x4;

#define QLIM 127.0f

// ---------------- fused quantize: x and w in one dispatch ----------------
__global__ __launch_bounds__(256) void quantize_fused(
    const float4* __restrict__ x, const float4* __restrict__ w,
    int* __restrict__ q,                       // qx (nx4 ints) then qw
    const float* __restrict__ amax, const float* __restrict__ amax_w,
    long nx4, long ntot4)
{
    const float sx = QLIM / amax[0];
    const float sw = QLIM / amax_w[0];
    const long stride = (long)gridDim.x * blockDim.x;
    for (long i = (long)blockIdx.x * blockDim.x + threadIdx.x; i < ntot4; i += stride) {
        const bool isx = i < nx4;
        const float4 v = isx ? x[i] : w[i - nx4];
        const float s  = isx ? sx : sw;
        float a0 = rintf(fminf(fmaxf(v.x * s, -QLIM), QLIM));
        float a1 = rintf(fminf(fmaxf(v.y * s, -QLIM), QLIM));
        float a2 = rintf(fminf(fmaxf(v.z * s, -QLIM), QLIM));
        float a3 = rintf(fminf(fmaxf(v.w * s, -QLIM), QLIM));
        q[i] = ((int)a0 & 255) | (((int)a1 & 255) << 8) |
               (((int)a2 & 255) << 16) | (((int)a3 & 255) << 24);
    }
}

// ---------------- 256x256 8-phase i8 GEMM (T2+T3+T4+T5) ----------------
// C[M][N] = A[M][K] * B[N][K]^T, fp32 epilogue.
// LDS layout per matrix: [buf(2)][kh(2)][row(256)][64B], swizzled:
//   physical_col = logical_col ^ (((row>>1)&3)<<4)   (involution)
// Staging writes linear LDS (global_load_lds) from inverse-swizzled global src.
// Phase schedule per K-tile t (4 phases): (kk0,m0-3), (kk0,m4-7), (kk1,m0-3), (kk1,m4-7)
// Stage map: ph0->A-kh1(t+1), ph1->B-kh1(t+1), ph2->A-kh0(t+2), ph3->B-kh0(t+2)
// vmcnt(4) once per tile at ph3 (vmcnt(0) in last 2 tiles).

#define STAGE(mat, tt, kh) do {                                              \
    if ((tt) < nt) {                                                         \
        const size_t go = (size_t)((tt) * 128 + (kh) * 64);                  \
        const int ld = ((((tt) & 1) << 15) | ((kh) << 14));                  \
        __builtin_amdgcn_global_load_lds(                                    \
            (const __attribute__((address_space(1))) void*)(mat##Src + go),  \
            (__attribute__((address_space(3))) void*)(lds + mat##Dst + ld),  \
            16, 0, 0);                                                       \
        __builtin_amdgcn_global_load_lds(                                    \
            (const __attribute__((address_space(1))) void*)(mat##Src + go + rowStep), \
            (__attribute__((address_space(3))) void*)(lds + mat##Dst + ld + 8192),    \
            16, 0, 0);                                                       \
    }                                                                        \
} while (0)

__global__ __launch_bounds__(512, 2) void gemm_i8_8phase(
    const signed char* __restrict__ A,   // qx [M][K]
    const signed char* __restrict__ B,   // qw [N][K]
    const float* __restrict__ bias,
    const float* __restrict__ amax,
    const float* __restrict__ amax_w,
    float* __restrict__ C,
    int M, int N, int K)
{
    __shared__ signed char lds[131072];  // A: 0..64K, B: 64K..128K

    const int tid  = threadIdx.x;        // 0..511
    const int wid  = tid >> 6;           // 0..7
    const int lane = tid & 63;
    const int wr   = wid >> 2;           // 0..1  A-row half (128 rows)
    const int wc   = wid & 3;            // 0..3  B-col quarter (64 rows)
    const int bn   = blockIdx.x;
    const int bm   = blockIdx.y;
    const int nt   = K >> 7;             // K-tiles of 128 bytes

    const int fr   = lane & 15;
    const int fk   = (lane >> 4) << 4;
    const int fswz = ((fr >> 1) & 3) << 4;

    // LDS read bases (byte offsets); + m*1024 / n*1024 + kk*16384 + buf*32768
    const int aRd = (wr * 128 + fr) * 64 + (fk ^ fswz);
    const int bRd = 65536 + (wc * 64 + fr) * 64 + (fk ^ fswz);

    // staging: thread t -> row (t>>2) (+128 for 2nd load), 16B chunk (t&3),
    // global col pre-inverse-swizzled so linear LDS dest holds swizzled layout
    const int srow = tid >> 2;                                  // 0..127
    const int csw  = (((tid & 3) ^ ((tid >> 3) & 3)) << 4);
    const signed char* aSrc = A + (size_t)(bm * 256 + srow) * K + csw;
    const signed char* bSrc = B + (size_t)(bn * 256 + srow) * K + csw;
    const size_t rowStep = (size_t)128 * K;
    const int aDst = wid << 10;                 // + buf*32768 + kh*16384 (+8192 2nd load)
    const int bDst = 65536 + (wid << 10);

    i32x4 acc[8][4] = {};

    // ---- prologue: tile0 all 4 half-units + tile1 kh0 units ----
    STAGE(a, 0, 0); STAGE(b, 0, 0); STAGE(a, 0, 1); STAGE(b, 0, 1);
    STAGE(a, 1, 0); STAGE(b, 1, 0);
    asm volatile("s_waitcnt vmcnt(4)" ::: "memory");   // retire tile0's 8 loads
    __builtin_amdgcn_s_barrier();

#pragma unroll 1
    for (int t = 0; t < nt; ++t) {
        const int bb = (t & 1) << 15;
        const signed char* pa = lds + bb + aRd;
        const signed char* pb = lds + bb + bRd;
        i32x4 af[4], bf[4];

        // ---------- phase 0: kk=0, m 0-3 ----------
#pragma unroll
        for (int mm = 0; mm < 4; ++mm) af[mm] = *(const i32x4*)(pa + mm * 1024);
#pragma unroll
        for (int nn = 0; nn < 4; ++nn) bf[nn] = *(const i32x4*)(pb + nn * 1024);
        STAGE(a, t + 1, 1);
        __builtin_amdgcn_s_barrier();
        asm volatile("s_waitcnt lgkmcnt(0)" ::: "memory");
        __builtin_amdgcn_sched_barrier(0);
        __builtin_amdgcn_s_setprio(1);
#pragma unroll
        for (int mm = 0; mm < 4; ++mm)
#pragma unroll
            for (int nn = 0; nn < 4; ++nn)
                acc[mm][nn] = __builtin_amdgcn_mfma_i32_16x16x64_i8(af[mm], bf[nn], acc[mm][nn], 0, 0, 0);
        __builtin_amdgcn_s_setprio(0);
        __builtin_amdgcn_s_barrier();

        // ---------- phase 1: kk=0, m 4-7 (reuse bf) ----------
#pragma unroll
        for (int mm = 0; mm < 4; ++mm) af[mm] = *(const i32x4*)(pa + 4096 + mm * 1024);
        STAGE(b, t + 1, 1);
        __builtin_amdgcn_s_barrier();
        asm volatile("s_waitcnt lgkmcnt(0)" ::: "memory");
        __builtin_amdgcn_sched_barrier(0);
        __builtin_amdgcn_s_setprio(1);
#pragma unroll
        for (int mm = 0; mm < 4; ++mm)
#pragma unroll
            for (int nn = 0; nn < 4; ++nn)
                acc[4 + mm][nn] = __builtin_amdgcn_mfma_i32_16x16x64_i8(af[mm], bf[nn], acc[4 + mm][nn], 0, 0, 0);
        __builtin_amdgcn_s_setprio(0);
        __builtin_amdgcn_s_barrier();

        // ---------- phase 2: kk=1, m 0-3 ----------
#pragma unroll
        for (int mm = 0; mm < 4; ++mm) af[mm] = *(const i32x4*)(pa + 16384 + mm * 1024);
#pragma unroll
        for (int nn = 0; nn < 4; ++nn) bf[nn] = *(const i32x4*)(pb + 16384 + nn * 1024);
        STAGE(a, t + 2, 0);
        __builtin_amdgcn_s_barrier();
        asm volatile("s_waitcnt lgkmcnt(0)" ::: "memory");
        __builtin_amdgcn_sched_barrier(0);
        __builtin_amdgcn_s_setprio(1);
#pragma unroll
        for (int mm = 0; mm < 4; ++mm)
#pragma unroll
            for (int nn = 0; nn < 4; ++nn)
                acc[mm][nn] = __builtin_amdgcn_mfma_i32_16x16x64_i8(af[mm], bf[nn], acc[mm][nn], 0, 0, 0);
        __builtin_amdgcn_s_setprio(0);
        __builtin_amdgcn_s_barrier();

        // ---------- phase 3: kk=1, m 4-7 (reuse bf) ----------
#pragma unroll
        for (int mm = 0; mm < 4; ++mm) af[mm] = *(const i32x4*)(pa + 16384 + 4096 + mm * 1024);
        STAGE(b, t + 2, 0);
        __builtin_amdgcn_s_barrier();
        asm volatile("s_waitcnt lgkmcnt(0)" ::: "memory");
        __builtin_amdgcn_sched_barrier(0);
        __builtin_amdgcn_s_setprio(1);
#pragma unroll
        for (int mm = 0; mm < 4; ++mm)
#pragma unroll
            for (int nn = 0; nn < 4; ++nn)
                acc[4 + mm][nn] = __builtin_amdgcn_mfma_i32_16x16x64_i8(af[mm], bf[nn], acc[4 + mm][nn], 0, 0, 0);
        __builtin_amdgcn_s_setprio(0);
        if (t < nt - 2) asm volatile("s_waitcnt vmcnt(4)" ::: "memory");
        else            asm volatile("s_waitcnt vmcnt(0)" ::: "memory");
        __builtin_amdgcn_s_barrier();
    }

    // ---- epilogue ----
    const float sa  = QLIM / amax[0];
    const float sw  = QLIM / amax_w[0];
    const float inv = 1.0f / (sa * sw);
    const int row0 = bm * 256 + wr * 128;
    const int col0 = bn * 256 + wc * 64;
    const int rsub = (lane >> 4) << 2;
#pragma unroll
    for (int m = 0; m < 8; ++m) {
#pragma unroll
        for (int n = 0; n < 4; ++n) {
            const int colc = col0 + n * 16 + fr;
            const float bv = bias[colc];
#pragma unroll
            for (int r = 0; r < 4; ++r) {
                const int rowc = row0 + m * 16 + rsub + r;
                C[(size_t)rowc * N + colc] = (float)acc[m][n][r] * inv + bv;
            }
        }
    }
}

extern "C" void kernel_launch(void* const* d_in, const int* in_sizes, int n_in,
                              void* d_out, int out_size, void* d_ws, size_t ws_size,
                              hipStream_t stream) {
    const float* x      = (const float*)d_in[0];
    const float* w      = (const float*)d_in[1];
    const float* bias   = (const float*)d_in[2];
    const float* amax   = (const float*)d_in[3];
    const float* amax_w = (const float*)d_in[4];
    float* out = (float*)d_out;

    const int N = in_sizes[2];                 // 4096
    const int K = in_sizes[1] / N;             // 4096
    const int M = in_sizes[0] / K;             // 8192

    signed char* qx = (signed char*)d_ws;      // M*K (32 MB)
    signed char* qw = qx + (size_t)M * K;      // N*K (16 MB)

    const long nx4   = (long)M * K / 4;
    const long ntot4 = nx4 + (long)N * K / 4;
    quantize_fused<<<2048, 256, 0, stream>>>((const float4*)x, (const float4*)w,
                                             (int*)qx, amax, amax_w, nx4, ntot4);

    dim3 grid(N / 256, M / 256);               // (16, 32) = 512 blocks
    gemm_i8_8phase<<<grid, 512, 0, stream>>>(qx, qw, bias, amax, amax_w, out, M, N, K);
}